// Round 1
// baseline (881.975 us; speedup 1.0000x reference)
//
#include <hip/hip_runtime.h>

#define NB 32
#define NF 256
#define NT 4096
#define PAD_LEN 256

#define TF 32
#define TT 128

// f32 gaussian weights: exp(-0.5*c^2)/sum, c=-2..2, sigma=1
#define G0 0.054488684f
#define G1 0.24420134f
#define G2 0.40261995f

__device__ __forceinline__ int reflectF(int i) {
    i = (i < 0) ? -i : i;
    return (i >= NF) ? (2 * NF - 2 - i) : i;
}
__device__ __forceinline__ int reflectT(int i) {
    i = (i < 0) ? -i : i;
    return (i >= NT) ? (2 * NT - 2 - i) : i;
}
// order-preserving float->uint encoding for atomicMin/Max
__device__ __forceinline__ unsigned encf(float x) {
    unsigned u = __float_as_uint(x);
    return (u & 0x80000000u) ? ~u : (u | 0x80000000u);
}
__device__ __forceinline__ float decf(unsigned e) {
    unsigned u = (e & 0x80000000u) ? (e ^ 0x80000000u) : ~e;
    return __uint_as_float(u);
}

// ws layout: mm[NB][4] (mn,mx,mn2,mx2 encoded) @0 ; counts2[NB][NF][32] @1024 ; prefix2 @1024+1MB
#define MM_OFF 0
#define CNT_OFF 1024
#define PFX_OFF (1024 + NB * NF * 32 * 4)

__global__ __launch_bounds__(256) void k_init(float* __restrict__ out, unsigned* __restrict__ mm) {
    int tid = blockIdx.x * 256 + threadIdx.x;
    if (tid < NB * 3 * PAD_LEN) out[tid] = 0.0f;
    if (tid < NB) {
        mm[tid * 4 + 0] = 0xFFFFFFFFu;  // min spec
        mm[tid * 4 + 1] = 0u;           // max spec
        mm[tid * 4 + 2] = 0xFFFFFFFFu;  // min blur
        mm[tid * 4 + 3] = 0u;           // max blur
    }
}

__global__ __launch_bounds__(256) void k_minmax(const float* __restrict__ spec, unsigned* __restrict__ mm) {
    const int b = blockIdx.y;
    const float4* p = (const float4*)(spec + (size_t)b * NF * NT);
    const int base4 = blockIdx.x * 4096;  // 64 blocks/batch, 16384 elems each
    float lmin = __builtin_inff(), lmax = -__builtin_inff();
    for (int i = threadIdx.x; i < 4096; i += 256) {
        float4 v = p[base4 + i];
        lmin = fminf(lmin, fminf(fminf(v.x, v.y), fminf(v.z, v.w)));
        lmax = fmaxf(lmax, fmaxf(fmaxf(v.x, v.y), fmaxf(v.z, v.w)));
    }
    for (int off = 32; off; off >>= 1) {
        lmin = fminf(lmin, __shfl_down(lmin, off));
        lmax = fmaxf(lmax, __shfl_down(lmax, off));
    }
    __shared__ float rmn[4], rmx[4];
    int wave = threadIdx.x >> 6, lane = threadIdx.x & 63;
    if (lane == 0) { rmn[wave] = lmin; rmx[wave] = lmax; }
    __syncthreads();
    if (threadIdx.x == 0) {
        for (int w = 1; w < 4; w++) { lmin = fminf(lmin, rmn[w]); lmax = fmaxf(lmax, rmx[w]); }
        atomicMin(&mm[b * 4 + 0], encf(lmin));
        atomicMax(&mm[b * 4 + 1], encf(lmax));
    }
}

// MODE 0: min/max of blur ; MODE 1: per-(row,chunk) positive-peak counts ; MODE 2: ranked extraction
template <int MODE>
__global__ __launch_bounds__(256) void k_blur(const float* __restrict__ spec, unsigned* __restrict__ mm,
                                              int* __restrict__ counts2, const int* __restrict__ prefix2,
                                              float* __restrict__ out) {
    const int b = blockIdx.z;
    const int f0 = blockIdx.y * TF;
    const int t0 = blockIdx.x * TT;
    const int c0 = blockIdx.x;

    if (MODE == 2) {
        // prefix is monotone in row-major (f,chunk) order; tile min is at (f0,c0)
        if (prefix2[(b * NF + f0) * 32 + c0] >= PAD_LEN) return;
    }

    __shared__ float sS[40 * 136];  // spec tile rows f0-4..f0+35, cols t0-4..t0+131; reused as sB
    __shared__ float sP[38 * 134];  // p1 rows f0-3..f0+34, cols t0-3..t0+130
    __shared__ float sV[34 * 134];  // vert-blur rows f0-1..f0+32, cols t0-3..t0+130
    float* sB = sS;                 // blur rows f0-1..f0+32, cols t0-1..t0+128 (34x130)

    const int tid = threadIdx.x;
    const float NEG = -__builtin_inff();
    const float mn = decf(mm[b * 4 + 0]);
    const float mx = decf(mm[b * 4 + 1]);
    const float rinv = 1.0f / (mx - mn);
    float mn2 = 0.0f, rinv2 = 0.0f;
    if (MODE >= 1) {
        mn2 = decf(mm[b * 4 + 2]);
        float mx2 = decf(mm[b * 4 + 3]);
        rinv2 = 1.0f / (mx2 - mn2);
    }
    const float* sb_base = spec + (size_t)b * NF * NT;

    // Phase A: stage spec tile (+4 halo), OOB = -inf
    for (int i = tid; i < 40 * 136; i += 256) {
        int r = i / 136, c = i - r * 136;
        int gf = f0 - 4 + r, gc = t0 - 4 + c;
        float v = NEG;
        if ((unsigned)gf < NF && (unsigned)gc < NT) v = sb_base[gf * NT + gc];
        sS[i] = v;
    }
    __syncthreads();

    // Phase B: p1 = isPeak(spec) ? (spec-mn)*rinv : 0
    for (int i = tid; i < 38 * 134; i += 256) {
        int r = i / 134, c = i - r * 134;
        int gf = f0 - 3 + r, gc = t0 - 3 + c;
        float v = 0.0f;
        if ((unsigned)gf < NF && (unsigned)gc < NT) {
            const float x  = sS[(r + 1) * 136 + (c + 1)];
            const float xl = sS[(r + 1) * 136 + c];
            const float xr = sS[(r + 1) * 136 + (c + 2)];
            const float xu = sS[r * 136 + (c + 1)];
            const float xd = sS[(r + 2) * 136 + (c + 1)];
            if (x >= xl && x >= xr && x >= xu && x >= xd) v = (x - mn) * rinv;
        }
        sP[i] = v;
    }
    __syncthreads();

    // Phase C: vertical 5-tap conv (reflect rows)
    for (int i = tid; i < 34 * 134; i += 256) {
        int r = i / 134, c = i - r * 134;
        int gf = f0 - 1 + r, gc = t0 - 3 + c;
        float acc = 0.0f;
        if ((unsigned)gf < NF && (unsigned)gc < NT) {
            int rm2 = reflectF(gf - 2) - (f0 - 3);
            int rm1 = reflectF(gf - 1) - (f0 - 3);
            int rcc = gf - (f0 - 3);
            int rp1 = reflectF(gf + 1) - (f0 - 3);
            int rp2 = reflectF(gf + 2) - (f0 - 3);
            acc  = G0 * sP[rm2 * 134 + c];
            acc += G1 * sP[rm1 * 134 + c];
            acc += G2 * sP[rcc * 134 + c];
            acc += G1 * sP[rp1 * 134 + c];
            acc += G0 * sP[rp2 * 134 + c];
        }
        sV[i] = acc;
    }
    __syncthreads();

    // Phase D: horizontal 5-tap conv (reflect cols) -> sB (overlays sS); OOB = -inf
    for (int i = tid; i < 34 * 130; i += 256) {
        int r = i / 130, c = i - r * 130;
        int gf = f0 - 1 + r, gc = t0 - 1 + c;
        float acc = NEG;
        if ((unsigned)gf < NF && (unsigned)gc < NT) {
            int cm2 = reflectT(gc - 2) - (t0 - 3);
            int cm1 = reflectT(gc - 1) - (t0 - 3);
            int ccc = gc - (t0 - 3);
            int cp1 = reflectT(gc + 1) - (t0 - 3);
            int cp2 = reflectT(gc + 2) - (t0 - 3);
            const float* vr = sV + r * 134;
            acc  = G0 * vr[cm2];
            acc += G1 * vr[cm1];
            acc += G2 * vr[ccc];
            acc += G1 * vr[cp1];
            acc += G0 * vr[cp2];
        }
        sB[i] = acc;
    }
    __syncthreads();

    if (MODE == 0) {
        float lmin = __builtin_inff(), lmax = -__builtin_inff();
        for (int i = tid; i < TF * TT; i += 256) {
            int r = i >> 7, c = i & 127;
            float v = sB[(r + 1) * 130 + (c + 1)];
            lmin = fminf(lmin, v);
            lmax = fmaxf(lmax, v);
        }
        for (int off = 32; off; off >>= 1) {
            lmin = fminf(lmin, __shfl_down(lmin, off));
            lmax = fmaxf(lmax, __shfl_down(lmax, off));
        }
        __shared__ float rmn[4], rmx[4];
        int wave = tid >> 6, lane = tid & 63;
        if (lane == 0) { rmn[wave] = lmin; rmx[wave] = lmax; }
        __syncthreads();
        if (tid == 0) {
            for (int w = 1; w < 4; w++) { lmin = fminf(lmin, rmn[w]); lmax = fmaxf(lmax, rmx[w]); }
            atomicMin(&mm[b * 4 + 2], encf(lmin));
            atomicMax(&mm[b * 4 + 3], encf(lmax));
        }
    } else if (MODE == 1) {
        const int r = tid >> 3, j = tid & 7;
        const float* bu = sB + r * 130;
        const float* bc = sB + (r + 1) * 130;
        const float* bd = sB + (r + 2) * 130;
        int cnt = 0;
        for (int q = 0; q < 16; q++) {
            int c = j * 16 + q;
            float x = bc[c + 1];
            bool pk = (x >= bc[c]) && (x >= bc[c + 2]) && (x >= bu[c + 1]) && (x >= bd[c + 1]);
            cnt += (pk && (x > mn2)) ? 1 : 0;
        }
        cnt += __shfl_down(cnt, 4, 8);
        cnt += __shfl_down(cnt, 2, 8);
        cnt += __shfl_down(cnt, 1, 8);
        if (j == 0) counts2[(b * NF + f0 + r) * 32 + c0] = cnt;
    } else {
        const int r = tid >> 3, j = tid & 7;
        const int gf = f0 + r;
        const int base = prefix2[(b * NF + gf) * 32 + c0];
        const float* bu = sB + r * 130;
        const float* bc = sB + (r + 1) * 130;
        const float* bd = sB + (r + 2) * 130;
        int mycnt = 0;
        if (base < PAD_LEN) {
            for (int q = 0; q < 16; q++) {
                int c = j * 16 + q;
                float x = bc[c + 1];
                bool pos = (x >= bc[c]) && (x >= bc[c + 2]) && (x >= bu[c + 1]) && (x >= bd[c + 1]) && (x > mn2);
                mycnt += pos ? 1 : 0;
            }
        }
        int scan = mycnt;
        for (int off = 1; off < 8; off <<= 1) {
            int v = __shfl_up(scan, off, 8);
            if (j >= off) scan += v;
        }
        int rank = base + (scan - mycnt);
        if (base < PAD_LEN) {
            for (int q = 0; q < 16 && rank < PAD_LEN; q++) {
                int c = j * 16 + q;
                float x = bc[c + 1];
                bool pos = (x >= bc[c]) && (x >= bc[c + 2]) && (x >= bu[c + 1]) && (x >= bd[c + 1]) && (x > mn2);
                if (pos) {
                    out[b * 768 + rank]        = (float)gf * (1.0f / 256.0f);
                    out[b * 768 + 256 + rank]  = (float)(t0 + c) * (1.0f / 4096.0f);
                    out[b * 768 + 512 + rank]  = (x - mn2) * rinv2;
                    rank++;
                }
            }
        }
    }
}

__global__ __launch_bounds__(256) void k_prefix(const int* __restrict__ counts2, int* __restrict__ prefix2) {
    const int b = blockIdx.x;
    const int tid = threadIdx.x;  // tid == freq row
    const int* cb = counts2 + b * NF * 32;
    int* pb = prefix2 + b * NF * 32;
    int local[32];
    int s = 0;
    for (int c = 0; c < 32; c++) {
        local[c] = cb[tid * 32 + c];
        s += local[c];
    }
    __shared__ int tot[256];
    tot[tid] = s;
    __syncthreads();
    for (int off = 1; off < 256; off <<= 1) {
        int v = (tid >= off) ? tot[tid - off] : 0;
        __syncthreads();
        tot[tid] += v;
        __syncthreads();
    }
    int run = tot[tid] - s;  // exclusive prefix of this row
    for (int c = 0; c < 32; c++) {
        pb[tid * 32 + c] = run;
        run += local[c];
    }
}

extern "C" void kernel_launch(void* const* d_in, const int* in_sizes, int n_in,
                              void* d_out, int out_size, void* d_ws, size_t ws_size,
                              hipStream_t stream) {
    const float* spec = (const float*)d_in[0];
    float* out = (float*)d_out;
    unsigned* mm = (unsigned*)((char*)d_ws + MM_OFF);
    int* counts2 = (int*)((char*)d_ws + CNT_OFF);
    int* prefix2 = (int*)((char*)d_ws + PFX_OFF);

    k_init<<<96, 256, 0, stream>>>(out, mm);
    k_minmax<<<dim3(64, NB), 256, 0, stream>>>(spec, mm);
    dim3 tgrid(NT / TT, NF / TF, NB);
    k_blur<0><<<tgrid, 256, 0, stream>>>(spec, mm, nullptr, nullptr, nullptr);
    k_blur<1><<<tgrid, 256, 0, stream>>>(spec, mm, counts2, nullptr, nullptr);
    k_prefix<<<NB, 256, 0, stream>>>(counts2, prefix2);
    k_blur<2><<<tgrid, 256, 0, stream>>>(spec, mm, nullptr, prefix2, out);
}

// Round 2
// 492.228 us; speedup vs baseline: 1.7918x; 1.7918x over previous
//
#include <hip/hip_runtime.h>

#define NB 32
#define NF 256
#define NT 4096
#define PAD_LEN 256

#define TF 32
#define TT 128

// f32 gaussian weights: exp(-0.5*c^2)/sum, c=-2..2, sigma=1
#define G0 0.054488684f
#define G1 0.24420134f
#define G2 0.40261995f

// LDS aliasing: region1 = sS(40x136) then sV(34x134); region2 = sP(38x134) then sB(34x130)
#define R1_WORDS (40 * 136)
#define R2_WORDS (38 * 134)

__device__ __forceinline__ int reflectF(int i) {
    i = (i < 0) ? -i : i;
    return (i >= NF) ? (2 * NF - 2 - i) : i;
}
__device__ __forceinline__ int reflectT(int i) {
    i = (i < 0) ? -i : i;
    return (i >= NT) ? (2 * NT - 2 - i) : i;
}
// order-preserving float->uint encoding for atomicMin/Max
__device__ __forceinline__ unsigned encf(float x) {
    unsigned u = __float_as_uint(x);
    return (u & 0x80000000u) ? ~u : (u | 0x80000000u);
}
__device__ __forceinline__ float decf(unsigned e) {
    unsigned u = (e & 0x80000000u) ? (e ^ 0x80000000u) : ~e;
    return __uint_as_float(u);
}

// ws layout: mm[NB][4] @0 ; counts2[NB][NF][32] @1024 ; prefix2 @1024+1MB
#define MM_OFF 0
#define CNT_OFF 1024
#define PFX_OFF (1024 + NB * NF * 32 * 4)

__global__ __launch_bounds__(256) void k_init(float* __restrict__ out, unsigned* __restrict__ mm) {
    int tid = blockIdx.x * 256 + threadIdx.x;
    if (tid < NB * 3 * PAD_LEN) out[tid] = 0.0f;
    if (tid < NB) {
        mm[tid * 4 + 0] = 0xFFFFFFFFu;  // min spec
        mm[tid * 4 + 1] = 0u;           // max spec
        mm[tid * 4 + 2] = 0xFFFFFFFFu;  // min blur
        mm[tid * 4 + 3] = 0u;           // max blur
    }
}

__global__ __launch_bounds__(256) void k_minmax(const float* __restrict__ spec, unsigned* __restrict__ mm) {
    const int b = blockIdx.y;
    const float4* p = (const float4*)(spec + (size_t)b * NF * NT);
    const int base4 = blockIdx.x * 4096;  // 64 blocks/batch
    float lmin = __builtin_inff(), lmax = -__builtin_inff();
    for (int i = threadIdx.x; i < 4096; i += 256) {
        float4 v = p[base4 + i];
        lmin = fminf(lmin, fminf(fminf(v.x, v.y), fminf(v.z, v.w)));
        lmax = fmaxf(lmax, fmaxf(fmaxf(v.x, v.y), fmaxf(v.z, v.w)));
    }
    for (int off = 32; off; off >>= 1) {
        lmin = fminf(lmin, __shfl_down(lmin, off));
        lmax = fmaxf(lmax, __shfl_down(lmax, off));
    }
    __shared__ float rmn[4], rmx[4];
    int wave = threadIdx.x >> 6, lane = threadIdx.x & 63;
    if (lane == 0) { rmn[wave] = lmin; rmx[wave] = lmax; }
    __syncthreads();
    if (threadIdx.x == 0) {
        for (int w = 1; w < 4; w++) { lmin = fminf(lmin, rmn[w]); lmax = fmaxf(lmax, rmx[w]); }
        atomicMin(&mm[b * 4 + 0], encf(lmin));
        atomicMax(&mm[b * 4 + 1], encf(lmax));
    }
}

// Computes the blurred-peak tile into sB (region2, layout [34][130]):
// rows f0-1..f0+32, cols t0-1..t0+128, OOB = -inf.
template <bool INT>
__device__ __forceinline__ void blur_tile(const float* __restrict__ sb_base,
                                          int f0, int t0, float mn, float rinv,
                                          float* sR1, float* sR2, int tid) {
    const float NEG = -__builtin_inff();
    float* sS = sR1;  // [40][136] spec tile, rows f0-4.., cols t0-4..
    float* sP = sR2;  // [38][134] p1, rows f0-3.., cols t0-3..
    float* sV = sR1;  // [34][134] vert blur, rows f0-1.., cols t0-3.. (overlays sS)
    float* sB = sR2;  // [34][130] blur, rows f0-1.., cols t0-1.. (overlays sP)

    // Phase A: stage spec (+4 halo)
    if (INT) {
        const float4* gp = (const float4*)(sb_base + (size_t)(f0 - 4) * NT + (t0 - 4));
        float4* s4 = (float4*)sS;  // row stride 34 float4
        for (int i = tid; i < 40 * 34; i += 256) {
            int r = i / 34, c = i - r * 34;
            s4[r * 34 + c] = gp[r * (NT / 4) + c];
        }
    } else {
        for (int i = tid; i < 40 * 136; i += 256) {
            int r = i / 136, c = i - r * 136;
            int gf = f0 - 4 + r, gc = t0 - 4 + c;
            float v = NEG;
            if ((unsigned)gf < NF && (unsigned)gc < NT) v = sb_base[gf * NT + gc];
            sS[i] = v;
        }
    }
    __syncthreads();

    // Phase B: p1 = isPeak(spec) ? (spec-mn)*rinv : 0
    if (INT) {
        for (int i = tid; i < 38 * 134; i += 256) {
            int r = i / 134, c = i - r * 134;
            const float* m = sS + (r + 1) * 136 + c;
            float x = m[1];
            float xu = sS[r * 136 + c + 1];
            float xd = sS[(r + 2) * 136 + c + 1];
            float v = 0.0f;
            if (x >= m[0] && x >= m[2] && x >= xu && x >= xd) v = (x - mn) * rinv;
            sP[i] = v;
        }
    } else {
        for (int i = tid; i < 38 * 134; i += 256) {
            int r = i / 134, c = i - r * 134;
            int gf = f0 - 3 + r, gc = t0 - 3 + c;
            float v = 0.0f;
            if ((unsigned)gf < NF && (unsigned)gc < NT) {
                const float x  = sS[(r + 1) * 136 + (c + 1)];
                const float xl = sS[(r + 1) * 136 + c];
                const float xr = sS[(r + 1) * 136 + (c + 2)];
                const float xu = sS[r * 136 + (c + 1)];
                const float xd = sS[(r + 2) * 136 + (c + 1)];
                if (x >= xl && x >= xr && x >= xu && x >= xd) v = (x - mn) * rinv;
            }
            sP[i] = v;
        }
    }
    __syncthreads();

    // Phase C: vertical 5-tap (reflect rows on boundary) -> sV (overlays sS)
    if (INT) {
        for (int i = tid; i < 34 * 134; i += 256) {
            int r = i / 134, c = i - r * 134;
            const float* p = sP + r * 134 + c;  // rows r..r+4 == gf-2..gf+2
            sV[i] = G0 * p[0] + G1 * p[134] + G2 * p[268] + G1 * p[402] + G0 * p[536];
        }
    } else {
        for (int i = tid; i < 34 * 134; i += 256) {
            int r = i / 134, c = i - r * 134;
            int gf = f0 - 1 + r, gc = t0 - 3 + c;
            float acc = 0.0f;
            if ((unsigned)gf < NF && (unsigned)gc < NT) {
                int rm2 = reflectF(gf - 2) - (f0 - 3);
                int rm1 = reflectF(gf - 1) - (f0 - 3);
                int rcc = gf - (f0 - 3);
                int rp1 = reflectF(gf + 1) - (f0 - 3);
                int rp2 = reflectF(gf + 2) - (f0 - 3);
                acc  = G0 * sP[rm2 * 134 + c];
                acc += G1 * sP[rm1 * 134 + c];
                acc += G2 * sP[rcc * 134 + c];
                acc += G1 * sP[rp1 * 134 + c];
                acc += G0 * sP[rp2 * 134 + c];
            }
            sV[i] = acc;
        }
    }
    __syncthreads();

    // Phase D: horizontal 5-tap (reflect cols on boundary) -> sB (overlays sP); OOB=-inf
    if (INT) {
        for (int i = tid; i < 34 * 130; i += 256) {
            int r = i / 130, c = i - r * 130;
            const float* v = sV + r * 134 + c;  // cols c..c+4 == gc-2..gc+2
            sB[i] = G0 * v[0] + G1 * v[1] + G2 * v[2] + G1 * v[3] + G0 * v[4];
        }
    } else {
        for (int i = tid; i < 34 * 130; i += 256) {
            int r = i / 130, c = i - r * 130;
            int gf = f0 - 1 + r, gc = t0 - 1 + c;
            float acc = NEG;
            if ((unsigned)gf < NF && (unsigned)gc < NT) {
                int cm2 = reflectT(gc - 2) - (t0 - 3);
                int cm1 = reflectT(gc - 1) - (t0 - 3);
                int ccc = gc - (t0 - 3);
                int cp1 = reflectT(gc + 1) - (t0 - 3);
                int cp2 = reflectT(gc + 2) - (t0 - 3);
                const float* vr = sV + r * 134;
                acc  = G0 * vr[cm2];
                acc += G1 * vr[cm1];
                acc += G2 * vr[ccc];
                acc += G1 * vr[cp1];
                acc += G0 * vr[cp2];
            }
            sB[i] = acc;
        }
    }
    __syncthreads();
}

// Main pass: blur + blur-min/max + per-(row,chunk) counts with threshold x > 0
// (valid when mn2 == 0, which holds because blur >= 0 and empty 5x5 windows exist;
//  k_fallback recounts with the true mn2 iff mn2 != 0)
__global__ __launch_bounds__(256) void k_main(const float* __restrict__ spec, unsigned* __restrict__ mm,
                                              int* __restrict__ counts2) {
    const int b = blockIdx.z;
    const int f0 = blockIdx.y * TF;
    const int t0 = blockIdx.x * TT;
    const int c0 = blockIdx.x;
    const int tid = threadIdx.x;

    __shared__ __align__(16) float sR1[R1_WORDS];
    __shared__ __align__(16) float sR2[R2_WORDS];
    float* sB = sR2;

    const float mn = decf(mm[b * 4 + 0]);
    const float mx = decf(mm[b * 4 + 1]);
    const float rinv = 1.0f / (mx - mn);
    const float* sb_base = spec + (size_t)b * NF * NT;

    const bool interior = (blockIdx.y >= 1 && blockIdx.y <= 6 && blockIdx.x >= 1 && blockIdx.x <= 30);
    if (interior) blur_tile<true>(sb_base, f0, t0, mn, rinv, sR1, sR2, tid);
    else          blur_tile<false>(sb_base, f0, t0, mn, rinv, sR1, sR2, tid);

    // Fused epilogue: per-row counts (x>0) + block min/max of blur interior
    const int r = tid >> 3, j = tid & 7;
    const float* bu = sB + r * 130;
    const float* bc = sB + (r + 1) * 130;
    const float* bd = sB + (r + 2) * 130;
    int cnt = 0;
    float lmin = __builtin_inff(), lmax = -__builtin_inff();
    for (int q = 0; q < 16; q++) {
        int c = j * 16 + q;
        float x = bc[c + 1];
        lmin = fminf(lmin, x);
        lmax = fmaxf(lmax, x);
        bool pk = (x >= bc[c]) && (x >= bc[c + 2]) && (x >= bu[c + 1]) && (x >= bd[c + 1]);
        cnt += (pk && (x > 0.0f)) ? 1 : 0;
    }
    int cs = cnt;
    cs += __shfl_down(cs, 4, 8);
    cs += __shfl_down(cs, 2, 8);
    cs += __shfl_down(cs, 1, 8);
    if (j == 0) counts2[(b * NF + f0 + r) * 32 + c0] = cs;

    for (int off = 32; off; off >>= 1) {
        lmin = fminf(lmin, __shfl_down(lmin, off));
        lmax = fmaxf(lmax, __shfl_down(lmax, off));
    }
    __shared__ float rmn[4], rmx[4];
    int wave = tid >> 6, lane = tid & 63;
    if (lane == 0) { rmn[wave] = lmin; rmx[wave] = lmax; }
    __syncthreads();
    if (tid == 0) {
        for (int w = 1; w < 4; w++) { lmin = fminf(lmin, rmn[w]); lmax = fmaxf(lmax, rmx[w]); }
        atomicMin(&mm[b * 4 + 2], encf(lmin));
        atomicMax(&mm[b * 4 + 3], encf(lmax));
    }
}

// Guard pass: only does work if mn2 != 0 (then k_main's x>0 counts were wrong);
// recounts with threshold x > mn2. Normally exits immediately.
__global__ __launch_bounds__(256) void k_fallback(const float* __restrict__ spec, unsigned* __restrict__ mm,
                                                  int* __restrict__ counts2) {
    const int b = blockIdx.z;
    const float mn2 = decf(mm[b * 4 + 2]);
    if (mn2 == 0.0f) return;

    const int f0 = blockIdx.y * TF;
    const int t0 = blockIdx.x * TT;
    const int c0 = blockIdx.x;
    const int tid = threadIdx.x;

    __shared__ __align__(16) float sR1[R1_WORDS];
    __shared__ __align__(16) float sR2[R2_WORDS];
    float* sB = sR2;

    const float mn = decf(mm[b * 4 + 0]);
    const float mx = decf(mm[b * 4 + 1]);
    const float rinv = 1.0f / (mx - mn);
    const float* sb_base = spec + (size_t)b * NF * NT;

    blur_tile<false>(sb_base, f0, t0, mn, rinv, sR1, sR2, tid);

    const int r = tid >> 3, j = tid & 7;
    const float* bu = sB + r * 130;
    const float* bc = sB + (r + 1) * 130;
    const float* bd = sB + (r + 2) * 130;
    int cnt = 0;
    for (int q = 0; q < 16; q++) {
        int c = j * 16 + q;
        float x = bc[c + 1];
        bool pk = (x >= bc[c]) && (x >= bc[c + 2]) && (x >= bu[c + 1]) && (x >= bd[c + 1]);
        cnt += (pk && (x > mn2)) ? 1 : 0;
    }
    cnt += __shfl_down(cnt, 4, 8);
    cnt += __shfl_down(cnt, 2, 8);
    cnt += __shfl_down(cnt, 1, 8);
    if (j == 0) counts2[(b * NF + f0 + r) * 32 + c0] = cnt;
}

__global__ __launch_bounds__(256) void k_prefix(const int* __restrict__ counts2, int* __restrict__ prefix2) {
    const int b = blockIdx.x;
    const int tid = threadIdx.x;  // tid == freq row
    const int* cb = counts2 + b * NF * 32;
    int* pb = prefix2 + b * NF * 32;
    int local[32];
    int s = 0;
    for (int c = 0; c < 32; c++) {
        local[c] = cb[tid * 32 + c];
        s += local[c];
    }
    __shared__ int tot[256];
    tot[tid] = s;
    __syncthreads();
    for (int off = 1; off < 256; off <<= 1) {
        int v = (tid >= off) ? tot[tid - off] : 0;
        __syncthreads();
        tot[tid] += v;
        __syncthreads();
    }
    int run = tot[tid] - s;  // exclusive prefix of this row
    for (int c = 0; c < 32; c++) {
        pb[tid * 32 + c] = run;
        run += local[c];
    }
}

__global__ __launch_bounds__(256) void k_extract(const float* __restrict__ spec, unsigned* __restrict__ mm,
                                                 const int* __restrict__ prefix2, float* __restrict__ out) {
    const int b = blockIdx.z;
    const int f0 = blockIdx.y * TF;
    const int t0 = blockIdx.x * TT;
    const int c0 = blockIdx.x;
    // prefix is monotone in row-major (f,chunk) order; tile min is at (f0,c0)
    if (prefix2[(b * NF + f0) * 32 + c0] >= PAD_LEN) return;

    const int tid = threadIdx.x;
    __shared__ __align__(16) float sR1[R1_WORDS];
    __shared__ __align__(16) float sR2[R2_WORDS];
    float* sB = sR2;

    const float mn = decf(mm[b * 4 + 0]);
    const float mx = decf(mm[b * 4 + 1]);
    const float rinv = 1.0f / (mx - mn);
    const float mn2 = decf(mm[b * 4 + 2]);
    const float mx2 = decf(mm[b * 4 + 3]);
    const float rinv2 = 1.0f / (mx2 - mn2);
    const float* sb_base = spec + (size_t)b * NF * NT;

    const bool interior = (blockIdx.y >= 1 && blockIdx.y <= 6 && blockIdx.x >= 1 && blockIdx.x <= 30);
    if (interior) blur_tile<true>(sb_base, f0, t0, mn, rinv, sR1, sR2, tid);
    else          blur_tile<false>(sb_base, f0, t0, mn, rinv, sR1, sR2, tid);

    const int r = tid >> 3, j = tid & 7;
    const int gf = f0 + r;
    const int base = prefix2[(b * NF + gf) * 32 + c0];
    const float* bu = sB + r * 130;
    const float* bc = sB + (r + 1) * 130;
    const float* bd = sB + (r + 2) * 130;
    int mycnt = 0;
    if (base < PAD_LEN) {
        for (int q = 0; q < 16; q++) {
            int c = j * 16 + q;
            float x = bc[c + 1];
            bool pos = (x >= bc[c]) && (x >= bc[c + 2]) && (x >= bu[c + 1]) && (x >= bd[c + 1]) && (x > mn2);
            mycnt += pos ? 1 : 0;
        }
    }
    int scan = mycnt;
    for (int off = 1; off < 8; off <<= 1) {
        int v = __shfl_up(scan, off, 8);
        if (j >= off) scan += v;
    }
    int rank = base + (scan - mycnt);
    if (base < PAD_LEN) {
        for (int q = 0; q < 16 && rank < PAD_LEN; q++) {
            int c = j * 16 + q;
            float x = bc[c + 1];
            bool pos = (x >= bc[c]) && (x >= bc[c + 2]) && (x >= bu[c + 1]) && (x >= bd[c + 1]) && (x > mn2);
            if (pos) {
                out[b * 768 + rank]        = (float)gf * (1.0f / 256.0f);
                out[b * 768 + 256 + rank]  = (float)(t0 + c) * (1.0f / 4096.0f);
                out[b * 768 + 512 + rank]  = (x - mn2) * rinv2;
                rank++;
            }
        }
    }
}

extern "C" void kernel_launch(void* const* d_in, const int* in_sizes, int n_in,
                              void* d_out, int out_size, void* d_ws, size_t ws_size,
                              hipStream_t stream) {
    const float* spec = (const float*)d_in[0];
    float* out = (float*)d_out;
    unsigned* mm = (unsigned*)((char*)d_ws + MM_OFF);
    int* counts2 = (int*)((char*)d_ws + CNT_OFF);
    int* prefix2 = (int*)((char*)d_ws + PFX_OFF);

    k_init<<<96, 256, 0, stream>>>(out, mm);
    k_minmax<<<dim3(64, NB), 256, 0, stream>>>(spec, mm);
    dim3 tgrid(NT / TT, NF / TF, NB);
    k_main<<<tgrid, 256, 0, stream>>>(spec, mm, counts2);
    k_fallback<<<tgrid, 256, 0, stream>>>(spec, mm, counts2);
    k_prefix<<<NB, 256, 0, stream>>>(counts2, prefix2);
    k_extract<<<tgrid, 256, 0, stream>>>(spec, mm, prefix2, out);
}

// Round 3
// 448.821 us; speedup vs baseline: 1.9651x; 1.0967x over previous
//
#include <hip/hip_runtime.h>

#define NB 32
#define NF 256
#define NT 4096
#define PAD_LEN 256

#define TF 16
#define TT 128

// f32 gaussian weights: exp(-0.5*c^2)/sum, c=-2..2, sigma=1
#define G0 0.054488684f
#define G1 0.24420134f
#define G2 0.40261995f

// All LDS arrays share column indexing: slot s <-> global col t0-4+s, s in [0,136)
// Row stride 136 floats (544B, 16B-aligned rows).
#define SW 136
#define SW4 34
#define RS 24   // sS rows: global f0-4 .. f0+19
#define RP 22   // sP rows: global f0-3 .. f0+18
#define RV 18   // sV/sB rows: global f0-1 .. f0+16

#define R1_WORDS (RS * SW)  // sS, overlaid by sV
#define R2_WORDS (RP * SW)  // sP, overlaid by sB

__device__ __forceinline__ int reflectF(int i) {
    i = (i < 0) ? -i : i;
    return (i >= NF) ? (2 * NF - 2 - i) : i;
}
__device__ __forceinline__ int reflectT(int i) {
    i = (i < 0) ? -i : i;
    return (i >= NT) ? (2 * NT - 2 - i) : i;
}
// order-preserving float->uint encoding for atomicMin/Max
__device__ __forceinline__ unsigned encf(float x) {
    unsigned u = __float_as_uint(x);
    return (u & 0x80000000u) ? ~u : (u | 0x80000000u);
}
__device__ __forceinline__ float decf(unsigned e) {
    unsigned u = (e & 0x80000000u) ? (e ^ 0x80000000u) : ~e;
    return __uint_as_float(u);
}

// ws layout: mm[NB][4] @0 ; counts2[NB][NF][32] @1024 ; prefix2 @1024+1MB
#define MM_OFF 0
#define CNT_OFF 1024
#define PFX_OFF (1024 + NB * NF * 32 * 4)

__global__ __launch_bounds__(256) void k_init(float* __restrict__ out, unsigned* __restrict__ mm) {
    int tid = blockIdx.x * 256 + threadIdx.x;
    if (tid < NB * 3 * PAD_LEN) out[tid] = 0.0f;
    if (tid < NB) {
        mm[tid * 4 + 0] = 0xFFFFFFFFu;
        mm[tid * 4 + 1] = 0u;
        mm[tid * 4 + 2] = 0xFFFFFFFFu;
        mm[tid * 4 + 3] = 0u;
    }
}

__global__ __launch_bounds__(256) void k_minmax(const float* __restrict__ spec, unsigned* __restrict__ mm) {
    const int b = blockIdx.y;
    const float4* p = (const float4*)(spec + (size_t)b * NF * NT);
    const int base4 = blockIdx.x * 4096;
    float lmin = __builtin_inff(), lmax = -__builtin_inff();
    for (int i = threadIdx.x; i < 4096; i += 256) {
        float4 v = p[base4 + i];
        lmin = fminf(lmin, fminf(fminf(v.x, v.y), fminf(v.z, v.w)));
        lmax = fmaxf(lmax, fmaxf(fmaxf(v.x, v.y), fmaxf(v.z, v.w)));
    }
    for (int off = 32; off; off >>= 1) {
        lmin = fminf(lmin, __shfl_down(lmin, off));
        lmax = fmaxf(lmax, __shfl_down(lmax, off));
    }
    __shared__ float rmn[4], rmx[4];
    int wave = threadIdx.x >> 6, lane = threadIdx.x & 63;
    if (lane == 0) { rmn[wave] = lmin; rmx[wave] = lmax; }
    __syncthreads();
    if (threadIdx.x == 0) {
        for (int w = 1; w < 4; w++) { lmin = fminf(lmin, rmn[w]); lmax = fmaxf(lmax, rmx[w]); }
        atomicMin(&mm[b * 4 + 0], encf(lmin));
        atomicMax(&mm[b * 4 + 1], encf(lmax));
    }
}

// Computes the blurred-peak tile into sB (region2): rows f0-1..f0+16 at rows 0..17,
// cols at slots 3..132 (t0-1..t0+128). OOB positions hold -inf.
template <bool INT>
__device__ __forceinline__ void blur_tile(const float* __restrict__ sb_base,
                                          int f0, int t0, float mn, float rinv,
                                          float* sR1, float* sR2, int tid) {
    const float NEG = -__builtin_inff();
    float* sS = sR1;
    float* sP = sR2;
    float* sV = sR1;  // overlays sS
    float* sB = sR2;  // overlays sP
    float4* sS4 = (float4*)sR1;
    float4* sP4 = (float4*)sR2;
    float4* sV4 = (float4*)sR1;
    float4* sB4 = (float4*)sR2;

    // Phase A: stage spec rows f0-4..f0+19, slots 0..135 (cols t0-4..t0+131)
    if (INT) {
        const float4* gp = (const float4*)(sb_base + (size_t)(f0 - 4) * NT + (t0 - 4));
        for (int i = tid; i < RS * SW4; i += 256) {
            int r = i / SW4, c = i - r * SW4;
            sS4[r * SW4 + c] = gp[r * (NT / 4) + c];
        }
    } else {
        for (int i = tid; i < RS * SW; i += 256) {
            int r = i / SW, c = i - r * SW;
            int gf = f0 - 4 + r, gc = t0 - 4 + c;
            float v = NEG;
            if ((unsigned)gf < NF && (unsigned)gc < NT) v = sb_base[gf * NT + gc];
            sS[i] = v;
        }
    }
    __syncthreads();

    // Phase B: p1 = isPeak(spec) ? (spec-mn)*rinv : 0 ; rows 0..21 (f0-3..f0+18)
    if (INT) {
        for (int i = tid; i < RP * SW4; i += 256) {
            int r = i / SW4, g = i - r * SW4;
            const float4 c4 = sS4[(r + 1) * SW4 + g];
            const float4 u4 = sS4[r * SW4 + g];
            const float4 d4 = sS4[(r + 2) * SW4 + g];
            const float lm = sS[(r + 1) * SW + 4 * g - 1];   // g==0: in-array garbage, masked below
            const float rp = sS[(r + 1) * SW + 4 * g + 4];   // g==33: in-array garbage, masked below
            float4 o;
            o.x = (c4.x >= lm   && c4.x >= c4.y && c4.x >= u4.x && c4.x >= d4.x) ? (c4.x - mn) * rinv : 0.0f;
            o.y = (c4.y >= c4.x && c4.y >= c4.z && c4.y >= u4.y && c4.y >= d4.y) ? (c4.y - mn) * rinv : 0.0f;
            o.z = (c4.z >= c4.y && c4.z >= c4.w && c4.z >= u4.z && c4.z >= d4.z) ? (c4.z - mn) * rinv : 0.0f;
            o.w = (c4.w >= c4.z && c4.w >= rp   && c4.w >= u4.w && c4.w >= d4.w) ? (c4.w - mn) * rinv : 0.0f;
            if (g == 0) o.x = 0.0f;
            if (g == 33) o.w = 0.0f;
            sP4[r * SW4 + g] = o;
        }
    } else {
        for (int i = tid; i < RP * 134; i += 256) {
            int r = i / 134, s = 1 + (i - r * 134);
            int gf = f0 - 3 + r, gc = t0 - 4 + s;
            float v = 0.0f;
            if ((unsigned)gf < NF && (unsigned)gc < NT) {
                const float x  = sS[(r + 1) * SW + s];
                const float xl = sS[(r + 1) * SW + s - 1];
                const float xr = sS[(r + 1) * SW + s + 1];
                const float xu = sS[r * SW + s];
                const float xd = sS[(r + 2) * SW + s];
                if (x >= xl && x >= xr && x >= xu && x >= xd) v = (x - mn) * rinv;
            }
            sP[r * SW + s] = v;
        }
    }
    __syncthreads();

    // Phase C: vertical 5-tap -> sV rows 0..17 (f0-1..f0+16)
    if (INT) {
        for (int i = tid; i < RV * SW4; i += 256) {
            int r = i / SW4, g = i - r * SW4;
            const float4 p0 = sP4[r * SW4 + g];
            const float4 p1 = sP4[(r + 1) * SW4 + g];
            const float4 p2 = sP4[(r + 2) * SW4 + g];
            const float4 p3 = sP4[(r + 3) * SW4 + g];
            const float4 p4 = sP4[(r + 4) * SW4 + g];
            float4 o;
            o.x = G0 * (p0.x + p4.x) + G1 * (p1.x + p3.x) + G2 * p2.x;
            o.y = G0 * (p0.y + p4.y) + G1 * (p1.y + p3.y) + G2 * p2.y;
            o.z = G0 * (p0.z + p4.z) + G1 * (p1.z + p3.z) + G2 * p2.z;
            o.w = G0 * (p0.w + p4.w) + G1 * (p1.w + p3.w) + G2 * p2.w;
            sV4[r * SW4 + g] = o;
        }
    } else {
        for (int i = tid; i < RV * 134; i += 256) {
            int r = i / 134, s = 1 + (i - r * 134);
            int gf = f0 - 1 + r, gc = t0 - 4 + s;
            float acc = 0.0f;
            if ((unsigned)gf < NF && (unsigned)gc < NT) {
                int rm2 = reflectF(gf - 2) - (f0 - 3);
                int rm1 = reflectF(gf - 1) - (f0 - 3);
                int rcc = gf - (f0 - 3);
                int rp1 = reflectF(gf + 1) - (f0 - 3);
                int rp2 = reflectF(gf + 2) - (f0 - 3);
                acc  = G0 * sP[rm2 * SW + s];
                acc += G1 * sP[rm1 * SW + s];
                acc += G2 * sP[rcc * SW + s];
                acc += G1 * sP[rp1 * SW + s];
                acc += G0 * sP[rp2 * SW + s];
            }
            sV[r * SW + s] = acc;
        }
    }
    __syncthreads();

    // Phase D: horizontal 5-tap -> sB rows 0..17, slots 3..132
    if (INT) {
        for (int i = tid; i < RV * 32; i += 256) {
            int r = i >> 5, g = 1 + (i & 31);
            const float4 A = sV4[r * SW4 + g - 1];
            const float4 B = sV4[r * SW4 + g];
            const float4 C = sV4[r * SW4 + g + 1];
            float4 o;
            o.x = G0 * (A.z + B.z) + G1 * (A.w + B.y) + G2 * B.x;
            o.y = G0 * (A.w + B.w) + G1 * (B.x + B.z) + G2 * B.y;
            o.z = G0 * (B.x + C.x) + G1 * (B.y + B.w) + G2 * B.z;
            o.w = G0 * (B.y + C.y) + G1 * (B.z + C.x) + G2 * B.w;
            sB4[r * SW4 + g] = o;
        }
        for (int i = tid; i < RV * 2; i += 256) {
            int r = i >> 1;
            int s = (i & 1) ? 132 : 3;
            const float* vr = sV + r * SW;
            sB[r * SW + s] = G0 * (vr[s - 2] + vr[s + 2]) + G1 * (vr[s - 1] + vr[s + 1]) + G2 * vr[s];
        }
    } else {
        for (int i = tid; i < RV * 130; i += 256) {
            int r = i / 130, s = 3 + (i - r * 130);
            int gf = f0 - 1 + r, gc = t0 - 4 + s;
            float acc = NEG;
            if ((unsigned)gf < NF && (unsigned)gc < NT) {
                int cm2 = reflectT(gc - 2) - (t0 - 4);
                int cm1 = reflectT(gc - 1) - (t0 - 4);
                int cp1 = reflectT(gc + 1) - (t0 - 4);
                int cp2 = reflectT(gc + 2) - (t0 - 4);
                const float* vr = sV + r * SW;
                acc  = G0 * (vr[cm2] + vr[cp2]);
                acc += G1 * (vr[cm1] + vr[cp1]);
                acc += G2 * vr[s];
            }
            sB[r * SW + s] = acc;
        }
    }
    __syncthreads();
}

// Epilogue helper: load the 8-col window for row r (global f0+r), octet m (cols t0+8m..+7)
struct Win8 {
    float c[8], l[8], rr[8], u[8], d[8];
};
__device__ __forceinline__ void load_win8(const float4* sB4, int r, int m, Win8& w) {
    const int g = 1 + 2 * m;
    const float4 Cm = sB4[(r + 1) * SW4 + g - 1];
    const float4 C0 = sB4[(r + 1) * SW4 + g];
    const float4 C1 = sB4[(r + 1) * SW4 + g + 1];
    const float4 C2 = sB4[(r + 1) * SW4 + g + 2];
    const float4 U0 = sB4[r * SW4 + g];
    const float4 U1 = sB4[r * SW4 + g + 1];
    const float4 D0 = sB4[(r + 2) * SW4 + g];
    const float4 D1 = sB4[(r + 2) * SW4 + g + 1];
    w.c[0] = C0.x; w.c[1] = C0.y; w.c[2] = C0.z; w.c[3] = C0.w;
    w.c[4] = C1.x; w.c[5] = C1.y; w.c[6] = C1.z; w.c[7] = C1.w;
    w.l[0] = Cm.w; w.l[1] = C0.x; w.l[2] = C0.y; w.l[3] = C0.z;
    w.l[4] = C0.w; w.l[5] = C1.x; w.l[6] = C1.y; w.l[7] = C1.z;
    w.rr[0] = C0.y; w.rr[1] = C0.z; w.rr[2] = C0.w; w.rr[3] = C1.x;
    w.rr[4] = C1.y; w.rr[5] = C1.z; w.rr[6] = C1.w; w.rr[7] = C2.x;
    w.u[0] = U0.x; w.u[1] = U0.y; w.u[2] = U0.z; w.u[3] = U0.w;
    w.u[4] = U1.x; w.u[5] = U1.y; w.u[6] = U1.z; w.u[7] = U1.w;
    w.d[0] = D0.x; w.d[1] = D0.y; w.d[2] = D0.z; w.d[3] = D0.w;
    w.d[4] = D1.x; w.d[5] = D1.y; w.d[6] = D1.z; w.d[7] = D1.w;
}

// Main pass: blur + blur-min/max + per-(row,chunk) counts with threshold x > 0
// (valid when mn2 == 0, which holds because blur >= 0 and empty 5x5 windows exist;
//  k_fallback recounts with the true mn2 iff mn2 != 0)
__global__ __launch_bounds__(256) void k_main(const float* __restrict__ spec, unsigned* __restrict__ mm,
                                              int* __restrict__ counts2) {
    const int b = blockIdx.z;
    const int f0 = blockIdx.y * TF;
    const int t0 = blockIdx.x * TT;
    const int c0 = blockIdx.x;
    const int tid = threadIdx.x;

    __shared__ __align__(16) float sR1[R1_WORDS];
    __shared__ __align__(16) float sR2[R2_WORDS];
    const float4* sB4 = (const float4*)sR2;

    const float mn = decf(mm[b * 4 + 0]);
    const float mx = decf(mm[b * 4 + 1]);
    const float rinv = 1.0f / (mx - mn);
    const float* sb_base = spec + (size_t)b * NF * NT;

    const bool interior = (blockIdx.y >= 1 && blockIdx.y <= 14 && blockIdx.x >= 1 && blockIdx.x <= 30);
    if (interior) blur_tile<true>(sb_base, f0, t0, mn, rinv, sR1, sR2, tid);
    else          blur_tile<false>(sb_base, f0, t0, mn, rinv, sR1, sR2, tid);

    const int r = tid >> 4, m = tid & 15;
    Win8 w;
    load_win8(sB4, r, m, w);
    int cnt = 0;
    float lmin = __builtin_inff(), lmax = -__builtin_inff();
#pragma unroll
    for (int k = 0; k < 8; k++) {
        float x = w.c[k];
        lmin = fminf(lmin, x);
        lmax = fmaxf(lmax, x);
        bool pk = (x >= w.l[k]) && (x >= w.rr[k]) && (x >= w.u[k]) && (x >= w.d[k]);
        cnt += (pk && (x > 0.0f)) ? 1 : 0;
    }
    int cs = cnt;
    cs += __shfl_down(cs, 8, 16);
    cs += __shfl_down(cs, 4, 16);
    cs += __shfl_down(cs, 2, 16);
    cs += __shfl_down(cs, 1, 16);
    if (m == 0) counts2[(b * NF + f0 + r) * 32 + c0] = cs;

    for (int off = 32; off; off >>= 1) {
        lmin = fminf(lmin, __shfl_down(lmin, off));
        lmax = fmaxf(lmax, __shfl_down(lmax, off));
    }
    __shared__ float rmn[4], rmx[4];
    int wave = tid >> 6, lane = tid & 63;
    if (lane == 0) { rmn[wave] = lmin; rmx[wave] = lmax; }
    __syncthreads();
    if (tid == 0) {
        for (int w2 = 1; w2 < 4; w2++) { lmin = fminf(lmin, rmn[w2]); lmax = fmaxf(lmax, rmx[w2]); }
        atomicMin(&mm[b * 4 + 2], encf(lmin));
        atomicMax(&mm[b * 4 + 3], encf(lmax));
    }
}

// Guard pass: only does work if mn2 != 0; recounts with threshold x > mn2.
__global__ __launch_bounds__(256) void k_fallback(const float* __restrict__ spec, unsigned* __restrict__ mm,
                                                  int* __restrict__ counts2) {
    const int b = blockIdx.z;
    const float mn2 = decf(mm[b * 4 + 2]);
    if (mn2 == 0.0f) return;

    const int f0 = blockIdx.y * TF;
    const int t0 = blockIdx.x * TT;
    const int c0 = blockIdx.x;
    const int tid = threadIdx.x;

    __shared__ __align__(16) float sR1[R1_WORDS];
    __shared__ __align__(16) float sR2[R2_WORDS];
    const float4* sB4 = (const float4*)sR2;

    const float mn = decf(mm[b * 4 + 0]);
    const float mx = decf(mm[b * 4 + 1]);
    const float rinv = 1.0f / (mx - mn);
    const float* sb_base = spec + (size_t)b * NF * NT;

    blur_tile<false>(sb_base, f0, t0, mn, rinv, sR1, sR2, tid);

    const int r = tid >> 4, m = tid & 15;
    Win8 w;
    load_win8(sB4, r, m, w);
    int cnt = 0;
#pragma unroll
    for (int k = 0; k < 8; k++) {
        float x = w.c[k];
        bool pk = (x >= w.l[k]) && (x >= w.rr[k]) && (x >= w.u[k]) && (x >= w.d[k]);
        cnt += (pk && (x > mn2)) ? 1 : 0;
    }
    cnt += __shfl_down(cnt, 8, 16);
    cnt += __shfl_down(cnt, 4, 16);
    cnt += __shfl_down(cnt, 2, 16);
    cnt += __shfl_down(cnt, 1, 16);
    if (m == 0) counts2[(b * NF + f0 + r) * 32 + c0] = cnt;
}

__global__ __launch_bounds__(256) void k_prefix(const int* __restrict__ counts2, int* __restrict__ prefix2) {
    const int b = blockIdx.x;
    const int tid = threadIdx.x;  // tid == freq row
    const int* cb = counts2 + b * NF * 32;
    int* pb = prefix2 + b * NF * 32;
    int local[32];
    int s = 0;
    for (int c = 0; c < 32; c++) {
        local[c] = cb[tid * 32 + c];
        s += local[c];
    }
    __shared__ int tot[256];
    tot[tid] = s;
    __syncthreads();
    for (int off = 1; off < 256; off <<= 1) {
        int v = (tid >= off) ? tot[tid - off] : 0;
        __syncthreads();
        tot[tid] += v;
        __syncthreads();
    }
    int run = tot[tid] - s;
    for (int c = 0; c < 32; c++) {
        pb[tid * 32 + c] = run;
        run += local[c];
    }
}

__global__ __launch_bounds__(256) void k_extract(const float* __restrict__ spec, unsigned* __restrict__ mm,
                                                 const int* __restrict__ prefix2, float* __restrict__ out) {
    const int b = blockIdx.z;
    const int f0 = blockIdx.y * TF;
    const int t0 = blockIdx.x * TT;
    const int c0 = blockIdx.x;
    // prefix is monotone in row-major (f,chunk) order; tile min is at (f0,c0)
    if (prefix2[(b * NF + f0) * 32 + c0] >= PAD_LEN) return;

    const int tid = threadIdx.x;
    __shared__ __align__(16) float sR1[R1_WORDS];
    __shared__ __align__(16) float sR2[R2_WORDS];
    const float4* sB4 = (const float4*)sR2;

    const float mn = decf(mm[b * 4 + 0]);
    const float mx = decf(mm[b * 4 + 1]);
    const float rinv = 1.0f / (mx - mn);
    const float mn2 = decf(mm[b * 4 + 2]);
    const float mx2 = decf(mm[b * 4 + 3]);
    const float rinv2 = 1.0f / (mx2 - mn2);
    const float* sb_base = spec + (size_t)b * NF * NT;

    const bool interior = (blockIdx.y >= 1 && blockIdx.y <= 14 && blockIdx.x >= 1 && blockIdx.x <= 30);
    if (interior) blur_tile<true>(sb_base, f0, t0, mn, rinv, sR1, sR2, tid);
    else          blur_tile<false>(sb_base, f0, t0, mn, rinv, sR1, sR2, tid);

    const int r = tid >> 4, m = tid & 15;
    const int gf = f0 + r;
    const int base = prefix2[(b * NF + gf) * 32 + c0];
    Win8 w;
    load_win8(sB4, r, m, w);
    bool pos[8];
    int mycnt = 0;
#pragma unroll
    for (int k = 0; k < 8; k++) {
        float x = w.c[k];
        pos[k] = (x >= w.l[k]) && (x >= w.rr[k]) && (x >= w.u[k]) && (x >= w.d[k]) && (x > mn2);
        mycnt += pos[k] ? 1 : 0;
    }
    int scan = mycnt;
    for (int off = 1; off < 16; off <<= 1) {
        int v = __shfl_up(scan, off, 16);
        if (m >= off) scan += v;
    }
    int rank = base + (scan - mycnt);
#pragma unroll
    for (int k = 0; k < 8; k++) {
        if (pos[k]) {
            if (rank < PAD_LEN) {
                int gc = t0 + 8 * m + k;
                out[b * 768 + rank]       = (float)gf * (1.0f / 256.0f);
                out[b * 768 + 256 + rank] = (float)gc * (1.0f / 4096.0f);
                out[b * 768 + 512 + rank] = (w.c[k] - mn2) * rinv2;
            }
            rank++;
        }
    }
}

extern "C" void kernel_launch(void* const* d_in, const int* in_sizes, int n_in,
                              void* d_out, int out_size, void* d_ws, size_t ws_size,
                              hipStream_t stream) {
    const float* spec = (const float*)d_in[0];
    float* out = (float*)d_out;
    unsigned* mm = (unsigned*)((char*)d_ws + MM_OFF);
    int* counts2 = (int*)((char*)d_ws + CNT_OFF);
    int* prefix2 = (int*)((char*)d_ws + PFX_OFF);

    k_init<<<96, 256, 0, stream>>>(out, mm);
    k_minmax<<<dim3(64, NB), 256, 0, stream>>>(spec, mm);
    dim3 tgrid(NT / TT, NF / TF, NB);
    k_main<<<tgrid, 256, 0, stream>>>(spec, mm, counts2);
    k_fallback<<<tgrid, 256, 0, stream>>>(spec, mm, counts2);
    k_prefix<<<NB, 256, 0, stream>>>(counts2, prefix2);
    k_extract<<<tgrid, 256, 0, stream>>>(spec, mm, prefix2, out);
}